// Round 1
// 1820.325 us; speedup vs baseline: 4.5248x; 4.5248x over previous
//
#include <hip/hip_runtime.h>
#include <stdint.h>

// PaddGRULayer: B=256, T=512, F=64, U=128. fp32 in/out.
// One persistent block per batch row (256 blocks x 512 threads, 1 block/CU).
// R1 change vs previous: stage-E weights (64 u32/thread = 136 u32 total demand
// > 128 allocated VGPRs) were spilling to scratch -> 10.6 GB HBM refetch/launch
// (158 B/thread/step). Moved wE to LDS (padded stride 68 -> conflict-free
// ds_read_b128), freeing 64 VGPRs so the remaining 72 weight u32 stay
// register-resident. Also: next-step input row prefetched into registers to
// hide HBM latency under the full step instead of stalling before B1.

#define T_STEPS 512
#define BDIM 512

typedef unsigned int u32;
typedef unsigned short u16;
typedef u32 u32x4 __attribute__((ext_vector_type(4)));

__device__ __forceinline__ u16 f2bf(float f) {
    u32 u = __float_as_uint(f);
    u32 r = (u + 0x7fffu + ((u >> 16) & 1u)) >> 16;  // RNE
    return (u16)r;
}
__device__ __forceinline__ u32 pack2(float a, float b) {
    return (u32)f2bf(a) | ((u32)f2bf(b) << 16);
}
__device__ __forceinline__ float lo_f(u32 u) { return __uint_as_float(u << 16); }
__device__ __forceinline__ float hi_f(u32 u) { return __uint_as_float(u & 0xffff0000u); }
__device__ __forceinline__ float sigm(float x) { return 1.0f / (1.0f + __expf(-x)); }
__device__ __forceinline__ float tanh_f(float x) { return 2.0f / (1.0f + __expf(-2.0f * x)) - 1.0f; }

__global__ __launch_bounds__(BDIM, 2)
void padd_gru_kernel(
    const float* __restrict__ xin,                       // [256,512,320]
    const float* __restrict__ h0,                        // [256,128]
    const float* __restrict__ ts0,                       // [256,64]
    const float* __restrict__ dt0,                       // [256,64]
    const float* __restrict__ w_reg, const float* __restrict__ b_reg,   // [128,64],[1]
    const float* __restrict__ w_ctl, const float* __restrict__ b_ctl,   // [128,64],[64]
    const float* __restrict__ w_dlt, const float* __restrict__ b_dlt,   // [64,128],[1]
    const float* __restrict__ w_vm,  const float* __restrict__ b_vm,    // [128,128],[1]
    const float* __restrict__ w_cor, const float* __restrict__ b_cor,   // [64,64],[64]
    const float* __restrict__ w_cat, const float* __restrict__ b_cat,   // [192,64],[1]
    const float* __restrict__ u_upd, const float* __restrict__ w_upd, const float* __restrict__ b_upd, // [128,128]x2,[1]
    const float* __restrict__ u_rst, const float* __restrict__ w_rst, const float* __restrict__ b_rst, // [128,128]x2,[1]
    float* __restrict__ out)
{
    const int t = threadIdx.x;
    const int b = blockIdx.x;

    __shared__ float h32[128];
    __shared__ float outbuf[320];   // [xreg(64) | zcorr(64) | c(64) | ts(64) | dt(64)] = output row order
    __shared__ float tv32[64];
    __shared__ float xcur32[64];
    __shared__ float cat32[192];    // [m(64) | decay(128)]  (stage D input)
    __shared__ float inE32[256];    // [dh(128) | c(64) | m(64)]  (stage E input)
    __shared__ float rdh32[128];
    __shared__ float red[512];
    __shared__ float red2[512];
    __shared__ float xs[320];
    __shared__ float bctl32[64];
    __shared__ float bcor32[64];
    // stage-E weight matrix, packed bf16 pairs. Row stride 68 u32 (68%32==4 ->
    // a wave64 ds_read_b128 covers all 32 banks in 8 service cycles, no excess
    // conflict; 272 B rows keep 16 B alignment). 2*256*68*4 = 136 KiB.
    __shared__ u32 wE_lds[2 * 256 * 68];

    const int jA = t & 127, sA = t >> 7;   // stages A/C1/F: col jA, 4-way K-split (sA wave-uniform)
    const int j8 = t & 63,  s8 = t >> 6;   // stages C2/D: col j8, 8-way K-split (s8 wave-uniform)
    const int jE = t & 255, sE = t >> 8;   // stage E: col jE, 2-way K-split (sE wave-uniform)

    // -------- register-resident packed-bf16 weights (72 u32/thread) --------
    u32 wA[16];    // [w_reg | w_ctl] col jA, k in [32*sA, +32)
    u32 wD[8];     // w_delta col jA, k in [16*sA, +16)
    u32 wC[4];     // w_corr (diag-masked) col j8, k in [8*s8, +8)
    u32 wCt[12];   // w_concat col j8, k in [24*s8, +24)
    u32 wF[32];    // col jA of [u_upd ; w_value_mask] (K=256), k in [64*sA, +64)

    {
        const float* src = (jA < 64) ? (w_reg + jA) : (w_ctl + (jA - 64));
        #pragma unroll
        for (int i = 0; i < 16; i++) {
            int k = 32 * sA + 2 * i;
            wA[i] = pack2(src[k * 64], src[(k + 1) * 64]);
        }
    }
    {
        #pragma unroll
        for (int i = 0; i < 8; i++) {
            int k = 16 * sA + 2 * i;
            wD[i] = pack2(w_dlt[k * 128 + jA], w_dlt[(k + 1) * 128 + jA]);
        }
    }
    {
        #pragma unroll
        for (int i = 0; i < 4; i++) {
            int k = 8 * s8 + 2 * i;
            float a = (k     == j8) ? 0.f : w_cor[k * 64 + j8];
            float c = (k + 1 == j8) ? 0.f : w_cor[(k + 1) * 64 + j8];
            wC[i] = pack2(a, c);
        }
    }
    {
        #pragma unroll
        for (int i = 0; i < 12; i++) {
            int k = 24 * s8 + 2 * i;
            wCt[i] = pack2(w_cat[k * 64 + j8], w_cat[(k + 1) * 64 + j8]);
        }
    }
    {
        // stage E matrix -> LDS: rows = [u_*(128) ; w_*(128)], cols = [upd(128) | rst(128)]
        // thread (sE, jE) owns the K-half sE of column jE: 64 packed u32, contiguous.
        const float* M = (jE < 128) ? (sE == 0 ? u_upd : w_upd)
                                    : (sE == 0 ? u_rst : w_rst);
        const float* src = M + (jE & 127);
        u32* wp = &wE_lds[(sE * 256 + jE) * 68];
        #pragma unroll
        for (int i = 0; i < 64; i++) {
            wp[i] = pack2(src[(2 * i) * 128], src[(2 * i + 1) * 128]);
        }
    }
    {
        // stage F matrix: rows = [u_upd(128) ; w_vm(128)], col jA, k in [64*sA,+64)
        const float* base = (sA < 2) ? (u_upd + (64 * sA) * 128 + jA)
                                     : (w_vm + (64 * (sA - 2)) * 128 + jA);
        #pragma unroll
        for (int i = 0; i < 32; i++) {
            wF[i] = pack2(base[(2 * i) * 128], base[(2 * i + 1) * 128]);
        }
    }

    const float bReg = b_reg[0];
    const float bDlt = b_dlt[0];
    const float bVm  = b_vm[0];
    const float bCat = b_cat[0];
    const float bUpd = b_upd[0];
    const float bRst = b_rst[0];

    if (t < 128) h32[t] = h0[(size_t)b * 128 + t];
    if (t < 64) {
        outbuf[192 + t] = ts0[(size_t)b * 64 + t];
        outbuf[256 + t] = dt0[(size_t)b * 64 + t];
        bctl32[t] = b_ctl[t];
        bcor32[t] = b_cor[t];
    }

    // prefetch first input row into registers (consumed at loop top)
    float2 xpre;
    xpre.x = 0.f; xpre.y = 0.f;
    if (t < 160) {
        const float2* xr0 = (const float2*)(xin + (size_t)b * 512 * 320);
        xpre = xr0[t];
    }

    __syncthreads();

    float zloc = 0.0f;  // z gate, persists E-combine -> F-combine (same thread t<128)

    for (int st = 0; st < T_STEPS; ++st) {
        // input row regs -> LDS, then issue next row's load (latency hidden under full step)
        if (t < 160) {
            xs[2 * t]     = xpre.x;
            xs[2 * t + 1] = xpre.y;
            int stn = (st + 1 < T_STEPS) ? (st + 1) : st;
            const float2* xr = (const float2*)(xin + ((size_t)b * 512 + stn) * 320);
            xpre = xr[t];
        }

        // ---- stage A: h @ [w_reg | w_ctl]  (K=128 -> N=128, 4-way k-split)
        {
            float a0 = 0.f, a1 = 0.f;
            const float* hp = &h32[32 * sA];
            #pragma unroll
            for (int i = 0; i < 16; i++) {
                u32 u = wA[i];
                a0 = fmaf(lo_f(u), hp[2 * i],     a0);
                a1 = fmaf(hi_f(u), hp[2 * i + 1], a1);
            }
            red[t] = a0 + a1;
        }
        __syncthreads();  // B1
        if (t < 128) {
            float s = red[t] + red[t + 128] + red[t + 256] + red[t + 384];
            if (t < 64) outbuf[t] = s + bReg;                     // x_reg
            else        tv32[t - 64] = fabsf(s + bctl32[t - 64]); // tv
        }
        __syncthreads();  // B2

        // ---- phase 2: elementwise ti/dt/x_cur (t<64)
        if (t < 64) {
            float ti_in = xs[t], x_in = xs[64 + t], m = xs[128 + t];
            float dt_in = xs[192 + t], pad = xs[256 + t];
            float pts = outbuf[192 + t], pdt = outbuf[256 + t];
            float tv = tv32[t], xrg = outbuf[t];
            float s   = pts + tv;
            float tic = pad * ti_in + (1.f - pad) * s;
            float tin = (tic <= 100.0f) ? tic : pts;
            float dg  = (s <= 100.0f) ? tv : pdt;
            float dtn = pad * dt_in + (1.f - pad) * dg;
            float xc  = m * x_in + (1.f - m) * xrg;
            outbuf[192 + t] = tin;   // ts (also output slice 3)
            outbuf[256 + t] = dtn;   // dt (also output slice 4)
            xcur32[t] = xc;
            cat32[t] = m;
            inE32[192 + t] = m;
        }
        __syncthreads();  // B3

        // ---- stage C: decay-pre (dt @ w_delta, 4-way) and z_corr (x_cur @ w_corr_masked, 8-way)
        {
            float a0 = 0.f, a1 = 0.f;
            const float* dp = &outbuf[256 + 16 * sA];
            #pragma unroll
            for (int i = 0; i < 8; i++) {
                u32 u = wD[i];
                a0 = fmaf(lo_f(u), dp[2 * i],     a0);
                a1 = fmaf(hi_f(u), dp[2 * i + 1], a1);
            }
            red[t] = a0 + a1;
            float c0 = 0.f, c1 = 0.f;
            const float* xp = &xcur32[8 * s8];
            #pragma unroll
            for (int i = 0; i < 4; i++) {
                u32 u = wC[i];
                c0 = fmaf(lo_f(u), xp[2 * i],     c0);
                c1 = fmaf(hi_f(u), xp[2 * i + 1], c1);
            }
            red2[t] = c0 + c1;
        }
        __syncthreads();  // B4
        if (t < 128) {
            float pre = red[t] + red[t + 128] + red[t + 256] + red[t + 384] + bDlt;
            float d = __expf(-fmaxf(pre, 0.f));     // decay
            cat32[64 + t] = d;
            inE32[t] = d * h32[t];                  // dh
            if (t < 64) {
                float zc = red2[t] + red2[64 + t] + red2[128 + t] + red2[192 + t]
                         + red2[256 + t] + red2[320 + t] + red2[384 + t] + red2[448 + t]
                         + bcor32[t];
                outbuf[64 + t] = zc;                // z_corr
            }
        }
        __syncthreads();  // B5

        // ---- stage D: beta-pre = [m, decay] @ w_concat (K=192 -> N=64, 8-way split)
        {
            float a0 = 0.f, a1 = 0.f;
            const float* cp = &cat32[24 * s8];
            #pragma unroll
            for (int i = 0; i < 12; i++) {
                u32 u = wCt[i];
                a0 = fmaf(lo_f(u), cp[2 * i],     a0);
                a1 = fmaf(hi_f(u), cp[2 * i + 1], a1);
            }
            red[t] = a0 + a1;
        }
        __syncthreads();  // B6
        if (t < 64) {
            float pre = red[t] + red[64 + t] + red[128 + t] + red[192 + t]
                      + red[256 + t] + red[320 + t] + red[384 + t] + red[448 + t]
                      + bCat;
            float beta = sigm(pre);
            float ct   = beta * outbuf[64 + t] + (1.f - beta) * outbuf[t];
            float m    = inE32[192 + t];
            float c    = m * xcur32[t] + (1.f - m) * ct;
            outbuf[128 + t] = c;
            inE32[128 + t]  = c;
        }
        __syncthreads();  // B7

        // ---- stage E: [dh|c|m](256) @ [[u_upd,u_rst],[w_upd,w_rst]]  (N=256, 2-way k-split)
        //      weights streamed from LDS as ds_read_b128 (conflict-free, stride 68)
        {
            float a0 = 0.f, a1 = 0.f, a2 = 0.f, a3 = 0.f;
            const float* ep = &inE32[128 * sE];
            const u32x4* wp = (const u32x4*)&wE_lds[(sE * 256 + jE) * 68];
            #pragma unroll
            for (int q = 0; q < 16; q++) {
                u32x4 w4 = wp[q];
                const float* e8 = ep + 8 * q;
                a0 = fmaf(lo_f(w4.x), e8[0], a0);
                a1 = fmaf(hi_f(w4.x), e8[1], a1);
                a2 = fmaf(lo_f(w4.y), e8[2], a2);
                a3 = fmaf(hi_f(w4.y), e8[3], a3);
                a0 = fmaf(lo_f(w4.z), e8[4], a0);
                a1 = fmaf(hi_f(w4.z), e8[5], a1);
                a2 = fmaf(lo_f(w4.w), e8[6], a2);
                a3 = fmaf(hi_f(w4.w), e8[7], a3);
            }
            red[t] = (a0 + a1) + (a2 + a3);
        }
        __syncthreads();  // B8
        // ---- E combine: z (kept in reg, t<128), r -> r*dh (t in [128,256)); plus output row store
        if (t < 256) {
            float val = red[t] + red[t + 256];
            if (t < 128) {
                zloc = sigm(val + bUpd);
            } else {
                float r = sigm(val + bRst);
                rdh32[t - 128] = r * inE32[t - 128];
            }
        }
        if (t < 160) {
            float2 v;
            v.x = outbuf[2 * t];
            v.y = outbuf[2 * t + 1];
            float2* orow = (float2*)(out + ((size_t)st * 256 + b) * 320);
            orow[t] = v;
        }
        __syncthreads();  // B9

        // ---- stage F: [r*dh | c | m](256) @ [u_upd ; w_value_mask] (N=128, 4-way k-split)
        {
            float a0 = 0.f, a1 = 0.f;
            const float* fp = (sA < 2) ? (rdh32 + 64 * sA) : (inE32 + 64 * sA);
            #pragma unroll
            for (int i = 0; i < 32; i++) {
                u32 u = wF[i];
                a0 = fmaf(lo_f(u), fp[2 * i],     a0);
                a1 = fmaf(hi_f(u), fp[2 * i + 1], a1);
            }
            red[t] = a0 + a1;
        }
        __syncthreads();  // B10
        if (t < 128) {
            float hh = tanh_f(red[t] + red[t + 128] + red[t + 256] + red[t + 384] + bVm);
            h32[t] = (1.f - zloc) * h32[t] + zloc * hh;
        }
        __syncthreads();  // B11
    }

    // final carry outputs: hT, tsT, dtT
    if (t < 128) out[(size_t)41943040u + (size_t)b * 128 + t] = h32[t];
    if (t < 64) {
        out[(size_t)41975808u + (size_t)b * 64 + t] = outbuf[192 + t];
        out[(size_t)41992192u + (size_t)b * 64 + t] = outbuf[256 + t];
    }
}

extern "C" void kernel_launch(void* const* d_in, const int* in_sizes, int n_in,
                              void* d_out, int out_size, void* d_ws, size_t ws_size,
                              hipStream_t stream) {
    const float* xin   = (const float*)d_in[0];
    const float* h0    = (const float*)d_in[1];
    const float* ts0   = (const float*)d_in[2];
    const float* dt0   = (const float*)d_in[3];
    const float* w_reg = (const float*)d_in[4];
    const float* b_reg = (const float*)d_in[5];
    const float* w_ctl = (const float*)d_in[6];
    const float* b_ctl = (const float*)d_in[7];
    const float* w_dlt = (const float*)d_in[8];
    const float* b_dlt = (const float*)d_in[9];
    const float* w_vm  = (const float*)d_in[10];
    const float* b_vm  = (const float*)d_in[11];
    const float* w_cor = (const float*)d_in[12];
    const float* b_cor = (const float*)d_in[13];
    const float* w_cat = (const float*)d_in[14];
    const float* b_cat = (const float*)d_in[15];
    const float* u_upd = (const float*)d_in[16];
    const float* w_upd = (const float*)d_in[17];
    const float* b_upd = (const float*)d_in[18];
    const float* u_rst = (const float*)d_in[19];
    const float* w_rst = (const float*)d_in[20];
    const float* b_rst = (const float*)d_in[21];

    padd_gru_kernel<<<dim3(256), dim3(BDIM), 0, stream>>>(
        xin, h0, ts0, dt0,
        w_reg, b_reg, w_ctl, b_ctl, w_dlt, b_dlt, w_vm, b_vm,
        w_cor, b_cor, w_cat, b_cat,
        u_upd, w_upd, b_upd, u_rst, w_rst, b_rst,
        (float*)d_out);
}

// Round 3
// 1564.973 us; speedup vs baseline: 5.2630x; 1.1632x over previous
//
#include <hip/hip_runtime.h>
#include <stdint.h>

// PaddGRULayer: B=256, T=512, F=64, U=128. fp32 in/out.
// One persistent block per batch row (256 blocks x 512 threads, 1 block/CU).
// R3 = R2 with the type fix: clang's cvt_pkrtz/fdot2 builtins use __fp16
// vectors, not _Float16.
// R2 changes vs R1 (1722 us, VALUBusy 42%, 11 barriers/step):
//  1. v_dot2_f32_f16 (__builtin_amdgcn_fdot2): weights AND activations packed
//     f16 pairs -> 1 inst / 2 MACs, no lo/hi unpack (~544 -> ~136 matmul inst).
//     Activations packed once per producer (cvt_pkrtz + lane shfl), not
//     unpacked per consumer. f16 has more mantissa than the bf16 this already
//     passed with; magnitudes <= 100 are safely in f16 range.
//  2. Intra-wave K-splits: column partials live in adjacent lanes of one wave,
//     reduced via __shfl_xor; leader lane writes result. Deletes red[]/red2[]
//     LDS round-trips and cuts barriers 11 -> 6 per step.

#define T_STEPS 512
#define BDIM 512

typedef unsigned int u32;
typedef u32 u32x4 __attribute__((ext_vector_type(4)));
typedef __fp16 f16;
typedef f16 h2 __attribute__((ext_vector_type(2)));

union pun { u32 u; h2 h; };
__device__ __forceinline__ u32 h2u(h2 h) { pun p; p.h = h; return p.u; }
__device__ __forceinline__ h2 u2h(u32 u) { pun p; p.u = u; return p.h; }
__device__ __forceinline__ h2 pkh(float a, float b) { return __builtin_amdgcn_cvt_pkrtz(a, b); }

__device__ __forceinline__ float dot2(h2 a, h2 b, float c) {
    return __builtin_amdgcn_fdot2(a, b, c, false);
}
__device__ __forceinline__ float sigm(float x) { return 1.0f / (1.0f + __expf(-x)); }
__device__ __forceinline__ float tanh_f(float x) { return 2.0f / (1.0f + __expf(-2.0f * x)) - 1.0f; }

__global__ __launch_bounds__(BDIM, 2)
void padd_gru_kernel(
    const float* __restrict__ xin,                       // [256,512,320]
    const float* __restrict__ h0,                        // [256,128]
    const float* __restrict__ ts0,                       // [256,64]
    const float* __restrict__ dt0,                       // [256,64]
    const float* __restrict__ w_reg, const float* __restrict__ b_reg,   // [128,64],[1]
    const float* __restrict__ w_ctl, const float* __restrict__ b_ctl,   // [128,64],[64]
    const float* __restrict__ w_dlt, const float* __restrict__ b_dlt,   // [64,128],[1]
    const float* __restrict__ w_vm,  const float* __restrict__ b_vm,    // [128,128],[1]
    const float* __restrict__ w_cor, const float* __restrict__ b_cor,   // [64,64],[64]
    const float* __restrict__ w_cat, const float* __restrict__ b_cat,   // [192,64],[1]
    const float* __restrict__ u_upd, const float* __restrict__ w_upd, const float* __restrict__ b_upd, // [128,128]x2,[1]
    const float* __restrict__ u_rst, const float* __restrict__ w_rst, const float* __restrict__ b_rst, // [128,128]x2,[1]
    float* __restrict__ out)
{
    const int t = threadIdx.x;
    const int b = blockIdx.x;

    // fp32 state / elementwise buffers
    __shared__ float h32[128];
    __shared__ float outbuf[320];   // [xreg | zcorr | c | ts | dt] = output row order
    __shared__ float tv32[64];
    __shared__ float xcur32[64];
    __shared__ float m32[64];
    __shared__ float dh32[128];
    __shared__ float z32[128];
    __shared__ float xs[320];
    __shared__ float bctl32[64];
    __shared__ float bcor32[64];
    // packed-f16 matmul activation buffers (u32 = h2 pair)
    __shared__ __align__(16) u32 hpk[64];     // h (stage A input)
    __shared__ __align__(16) u32 dtpk[32];    // dt (C1)
    __shared__ __align__(16) u32 xcpk[32];    // x_cur (C2)
    __shared__ __align__(16) u32 catpk[96];   // [m(32) | decay(64)] (D)
    __shared__ __align__(16) u32 epk[128];    // [dh(64) | c(32) | m(32)] (E; tail reused by F)
    __shared__ __align__(16) u32 rdhpk[64];   // r*dh (F)
    // stage-E weights, packed f16 pairs; row = thread t (col j2=t>>1, k-half s2=t&1),
    // stride 68 u32 (272 B): lane L bank = (L*68)&31 = 4L&31 -> 2 lanes/bank = free.
    __shared__ __align__(16) u32 wE_lds[512 * 68];

    const int s4 = t & 3, j4 = t >> 2;   // stages A, C1, F: 128 cols, 4-way intra-wave split
    const int s8 = t & 7, j8 = t >> 3;   // stages C2, D: 64 cols, 8-way
    const int s2 = t & 1, j2 = t >> 1;   // stage E: 256 cols, 2-way

    // -------- register-resident packed-f16 weights (72 u32/thread) --------
    h2 wA[16];    // [w_reg | w_ctl] col j4, k in [32*s4, +32)
    h2 wD[8];     // w_delta col j4, k in [16*s4, +16)
    h2 wC[4];     // w_corr (diag-masked) col j8, k in [8*s8, +8)
    h2 wCt[12];   // w_concat col j8, k in [24*s8, +24)
    h2 wF[32];    // [u_upd ; w_value_mask] col j4, k in [64*s4, +64)

    {
        const float* src = (j4 < 64) ? (w_reg + j4) : (w_ctl + (j4 - 64));
        #pragma unroll
        for (int i = 0; i < 16; i++) {
            int k = 32 * s4 + 2 * i;
            wA[i] = pkh(src[k * 64], src[(k + 1) * 64]);
        }
    }
    {
        #pragma unroll
        for (int i = 0; i < 8; i++) {
            int k = 16 * s4 + 2 * i;
            wD[i] = pkh(w_dlt[k * 128 + j4], w_dlt[(k + 1) * 128 + j4]);
        }
    }
    {
        #pragma unroll
        for (int i = 0; i < 4; i++) {
            int k = 8 * s8 + 2 * i;
            float a = (k     == j8) ? 0.f : w_cor[k * 64 + j8];
            float c = (k + 1 == j8) ? 0.f : w_cor[(k + 1) * 64 + j8];
            wC[i] = pkh(a, c);
        }
    }
    {
        #pragma unroll
        for (int i = 0; i < 12; i++) {
            int k = 24 * s8 + 2 * i;
            wCt[i] = pkh(w_cat[k * 64 + j8], w_cat[(k + 1) * 64 + j8]);
        }
    }
    {
        // stage E: rows = [u_*(128) ; w_*(128)] over [dh|c|m], cols = [upd | rst]
        const float* M = (j2 < 128) ? (s2 == 0 ? u_upd : w_upd)
                                    : (s2 == 0 ? u_rst : w_rst);
        const float* src = M + (j2 & 127);
        h2* wp = (h2*)&wE_lds[t * 68];
        #pragma unroll
        for (int i = 0; i < 64; i++) {
            wp[i] = pkh(src[(2 * i) * 128], src[(2 * i + 1) * 128]);
        }
    }
    {
        const float* base = (s4 < 2) ? (u_upd + (64 * s4) * 128 + j4)
                                     : (w_vm + (64 * (s4 - 2)) * 128 + j4);
        #pragma unroll
        for (int i = 0; i < 32; i++) {
            wF[i] = pkh(base[(2 * i) * 128], base[(2 * i + 1) * 128]);
        }
    }

    const float bReg = b_reg[0];
    const float bDlt = b_dlt[0];
    const float bVm  = b_vm[0];
    const float bCat = b_cat[0];
    const float bUpd = b_upd[0];
    const float bRst = b_rst[0];

    if (t < 128) h32[t] = h0[(size_t)b * 128 + t];
    if (t < 64) {
        outbuf[192 + t] = ts0[(size_t)b * 64 + t];
        outbuf[256 + t] = dt0[(size_t)b * 64 + t];
        bctl32[t] = b_ctl[t];
        bcor32[t] = b_cor[t];
        hpk[t] = h2u(pkh(h0[(size_t)b * 128 + 2 * t], h0[(size_t)b * 128 + 2 * t + 1]));
    }

    // prefetch first input row into registers (consumed at loop top)
    float2 xpre;
    xpre.x = 0.f; xpre.y = 0.f;
    if (t < 160) {
        xpre = ((const float2*)(xin + (size_t)b * 512 * 320))[t];
    }

    __syncthreads();

    for (int st = 0; st < T_STEPS; ++st) {
        // input row regs -> LDS; issue next row's load (hidden under full step)
        if (t < 160) {
            xs[2 * t]     = xpre.x;
            xs[2 * t + 1] = xpre.y;
            int stn = (st + 1 < T_STEPS) ? (st + 1) : st;
            xpre = ((const float2*)(xin + ((size_t)b * 512 + stn) * 320))[t];
        }

        // ---- stage A: h(128) @ [w_reg | w_ctl] -> 128 cols, 4-way intra-wave
        {
            const u32x4* hp = (const u32x4*)&hpk[16 * s4];
            float a0 = 0.f, a1 = 0.f;
            #pragma unroll
            for (int q = 0; q < 4; q++) {
                u32x4 h4 = hp[q];
                a0 = dot2(wA[4*q+0], u2h(h4.x), a0);
                a1 = dot2(wA[4*q+1], u2h(h4.y), a1);
                a0 = dot2(wA[4*q+2], u2h(h4.z), a0);
                a1 = dot2(wA[4*q+3], u2h(h4.w), a1);
            }
            float v = a0 + a1;
            v += __shfl_xor(v, 1);
            v += __shfl_xor(v, 2);
            if (s4 == 0) {
                if (j4 < 64) outbuf[j4] = v + bReg;                  // x_reg
                else         tv32[j4 - 64] = fabsf(v + bctl32[j4 - 64]);
            }
        }
        __syncthreads();  // B1

        // ---- phase 2: elementwise ti/dt/x_cur (wave 0) + pack producers
        if (t < 64) {
            float ti_in = xs[t], x_in = xs[64 + t], m = xs[128 + t];
            float dt_in = xs[192 + t], pad = xs[256 + t];
            float pts = outbuf[192 + t], pdt = outbuf[256 + t];
            float tv = tv32[t], xrg = outbuf[t];
            float sum = pts + tv;
            float tic = pad * ti_in + (1.f - pad) * sum;
            float tin = (tic <= 100.0f) ? tic : pts;
            float dg  = (sum <= 100.0f) ? tv : pdt;
            float dtn = pad * dt_in + (1.f - pad) * dg;
            float xc  = m * x_in + (1.f - m) * xrg;
            outbuf[192 + t] = tin;
            outbuf[256 + t] = dtn;
            xcur32[t] = xc;
            m32[t] = m;
            float dtn2 = __shfl_down(dtn, 1);
            float xc2  = __shfl_down(xc, 1);
            float m2   = __shfl_down(m, 1);
            if ((t & 1) == 0) {
                dtpk[t >> 1] = h2u(pkh(dtn, dtn2));
                xcpk[t >> 1] = h2u(pkh(xc, xc2));
                u32 mp = h2u(pkh(m, m2));
                catpk[t >> 1] = mp;
                epk[96 + (t >> 1)] = mp;
            }
        }
        __syncthreads();  // B2

        // ---- stage C: decay-pre (dt @ w_delta, 128 cols 4-way)
        //            +  z_corr   (x_cur @ w_corr_masked, 64 cols 8-way)
        {
            const u32x4* dp = (const u32x4*)&dtpk[8 * s4];
            float a0 = 0.f, a1 = 0.f;
            #pragma unroll
            for (int q = 0; q < 2; q++) {
                u32x4 d4 = dp[q];
                a0 = dot2(wD[4*q+0], u2h(d4.x), a0);
                a1 = dot2(wD[4*q+1], u2h(d4.y), a1);
                a0 = dot2(wD[4*q+2], u2h(d4.z), a0);
                a1 = dot2(wD[4*q+3], u2h(d4.w), a1);
            }
            float vd = a0 + a1;
            vd += __shfl_xor(vd, 1);
            vd += __shfl_xor(vd, 2);

            u32x4 x4 = *(const u32x4*)&xcpk[4 * s8];
            float c0 = dot2(wC[0], u2h(x4.x), 0.f);
            float c1 = dot2(wC[1], u2h(x4.y), 0.f);
            c0 = dot2(wC[2], u2h(x4.z), c0);
            c1 = dot2(wC[3], u2h(x4.w), c1);
            float vc = c0 + c1;
            vc += __shfl_xor(vc, 1);
            vc += __shfl_xor(vc, 2);
            vc += __shfl_xor(vc, 4);

            // combine: all lanes compute (group-uniform), leaders write
            float d  = __expf(-fmaxf(vd + bDlt, 0.f));   // decay
            float dh = d * h32[j4];
            float d2  = __shfl_down(d, 4);
            float dh2 = __shfl_down(dh, 4);
            if (s4 == 0) dh32[j4] = dh;
            if ((t & 7) == 0) {
                catpk[32 + (j4 >> 1)] = h2u(pkh(d, d2));
                epk[j4 >> 1]          = h2u(pkh(dh, dh2));
                outbuf[64 + j8] = vc + bcor32[j8];       // z_corr
            }
        }
        __syncthreads();  // B3

        // ---- stage D: beta-pre = [m, decay](192) @ w_concat -> 64 cols, 8-way
        {
            const u32x4* cp = (const u32x4*)&catpk[12 * s8];
            float a0 = 0.f, a1 = 0.f;
            #pragma unroll
            for (int q = 0; q < 3; q++) {
                u32x4 c4 = cp[q];
                a0 = dot2(wCt[4*q+0], u2h(c4.x), a0);
                a1 = dot2(wCt[4*q+1], u2h(c4.y), a1);
                a0 = dot2(wCt[4*q+2], u2h(c4.z), a0);
                a1 = dot2(wCt[4*q+3], u2h(c4.w), a1);
            }
            float v = a0 + a1;
            v += __shfl_xor(v, 1);
            v += __shfl_xor(v, 2);
            v += __shfl_xor(v, 4);
            float beta = sigm(v + bCat);
            float ct = beta * outbuf[64 + j8] + (1.f - beta) * outbuf[j8];
            float m  = m32[j8];
            float c  = m * xcur32[j8] + (1.f - m) * ct;
            float c2 = __shfl_down(c, 8);
            if (s8 == 0) outbuf[128 + j8] = c;
            if ((t & 15) == 0) epk[64 + (j8 >> 1)] = h2u(pkh(c, c2));
        }
        __syncthreads();  // B4

        // ---- stage E: [dh|c|m](256) @ [[u_upd,u_rst],[w_upd,w_rst]] -> 256 cols, 2-way
        //      (weights from LDS; output row store overlapped here)
        {
            const u32x4* wp = (const u32x4*)&wE_lds[t * 68];
            const u32x4* ep = (const u32x4*)&epk[64 * s2];
            float a0 = 0.f, a1 = 0.f, a2 = 0.f, a3 = 0.f;
            #pragma unroll
            for (int q = 0; q < 16; q++) {
                u32x4 w4 = wp[q];
                u32x4 e4 = ep[q];
                a0 = dot2(u2h(w4.x), u2h(e4.x), a0);
                a1 = dot2(u2h(w4.y), u2h(e4.y), a1);
                a2 = dot2(u2h(w4.z), u2h(e4.z), a2);
                a3 = dot2(u2h(w4.w), u2h(e4.w), a3);
            }
            float v = (a0 + a1) + (a2 + a3);
            v += __shfl_xor(v, 1);
            if (j2 < 128) {                  // wave-uniform branch (waves 0-3)
                float z = sigm(v + bUpd);
                if (s2 == 0) z32[j2] = z;
            } else {                         // waves 4-7
                float r = sigm(v + bRst);
                float rdh = r * dh32[j2 - 128];
                float rdh2 = __shfl_down(rdh, 2);
                if ((t & 3) == 0) rdhpk[(j2 - 128) >> 1] = h2u(pkh(rdh, rdh2));
            }
            if (t < 160) {
                float2 v2;
                v2.x = outbuf[2 * t];
                v2.y = outbuf[2 * t + 1];
                ((float2*)(out + ((size_t)st * 256 + b) * 320))[t] = v2;
            }
        }
        __syncthreads();  // B5

        // ---- stage F: [r*dh | c | m](256) @ [u_upd ; w_vm] -> 128 cols, 4-way
        {
            const u32x4* fp = (s4 & 2) ? (const u32x4*)&epk[64 + 32 * (s4 & 1)]
                                       : (const u32x4*)&rdhpk[32 * s4];
            float a0 = 0.f, a1 = 0.f;
            #pragma unroll
            for (int q = 0; q < 8; q++) {
                u32x4 f4 = fp[q];
                a0 = dot2(wF[4*q+0], u2h(f4.x), a0);
                a1 = dot2(wF[4*q+1], u2h(f4.y), a1);
                a0 = dot2(wF[4*q+2], u2h(f4.z), a0);
                a1 = dot2(wF[4*q+3], u2h(f4.w), a1);
            }
            float v = a0 + a1;
            v += __shfl_xor(v, 1);
            v += __shfl_xor(v, 2);
            float hh = tanh_f(v + bVm);
            float z = z32[j4];
            float hn = (1.f - z) * h32[j4] + z * hh;
            float hn2 = __shfl_down(hn, 4);
            if (s4 == 0) h32[j4] = hn;
            if ((t & 7) == 0) hpk[j4 >> 1] = h2u(pkh(hn, hn2));
        }
        __syncthreads();  // B6
    }

    // final carry outputs: hT, tsT, dtT
    if (t < 128) out[(size_t)41943040u + (size_t)b * 128 + t] = h32[t];
    if (t < 64) {
        out[(size_t)41975808u + (size_t)b * 64 + t] = outbuf[192 + t];
        out[(size_t)41992192u + (size_t)b * 64 + t] = outbuf[256 + t];
    }
}

extern "C" void kernel_launch(void* const* d_in, const int* in_sizes, int n_in,
                              void* d_out, int out_size, void* d_ws, size_t ws_size,
                              hipStream_t stream) {
    const float* xin   = (const float*)d_in[0];
    const float* h0    = (const float*)d_in[1];
    const float* ts0   = (const float*)d_in[2];
    const float* dt0   = (const float*)d_in[3];
    const float* w_reg = (const float*)d_in[4];
    const float* b_reg = (const float*)d_in[5];
    const float* w_ctl = (const float*)d_in[6];
    const float* b_ctl = (const float*)d_in[7];
    const float* w_dlt = (const float*)d_in[8];
    const float* b_dlt = (const float*)d_in[9];
    const float* w_vm  = (const float*)d_in[10];
    const float* b_vm  = (const float*)d_in[11];
    const float* w_cor = (const float*)d_in[12];
    const float* b_cor = (const float*)d_in[13];
    const float* w_cat = (const float*)d_in[14];
    const float* b_cat = (const float*)d_in[15];
    const float* u_upd = (const float*)d_in[16];
    const float* w_upd = (const float*)d_in[17];
    const float* b_upd = (const float*)d_in[18];
    const float* u_rst = (const float*)d_in[19];
    const float* w_rst = (const float*)d_in[20];
    const float* b_rst = (const float*)d_in[21];

    padd_gru_kernel<<<dim3(256), dim3(BDIM), 0, stream>>>(
        xin, h0, ts0, dt0,
        w_reg, b_reg, w_ctl, b_ctl, w_dlt, b_dlt, w_vm, b_vm,
        w_cor, b_cor, w_cat, b_cat,
        u_upd, w_upd, b_upd, u_rst, w_rst, b_rst,
        (float*)d_out);
}

// Round 4
// 1495.603 us; speedup vs baseline: 5.5072x; 1.0464x over previous
//
#include <hip/hip_runtime.h>
#include <stdint.h>

// PaddGRULayer: B=256, T=512, F=64, U=128. fp32 in/out.
// One persistent block per batch row (256 blocks x 512 threads, 1 block/CU).
// R4 change vs R3 (1424 us, VALUBusy 32%, SQ_LDS_BANK_CONFLICT 1.0e8):
//   Stage-E weights (64 u32/thread) moved from LDS back into VGPRs.
//   R3 streamed 128 KB/step of wE from LDS = hard 1024 cyc/step LDS-BW floor
//   plus ~768 conflict cyc/step (stride-68 b128 pattern). Total weight regs =
//   136 u32 + ~40 working ~= 180 VGPRs; R0's spill at the same demand was the
//   allocator targeting a 128-VGPR bucket for 4 waves/EU it can never have
//   (LDS+grid force 1 block/CU = 2 waves/EU). amdgpu_waves_per_eu(2,2) pins
//   the target so the allocator gets the full 256-VGPR budget.
//   Canary: FETCH_SIZE must stay ~84 MB (spill would balloon it).

#define T_STEPS 512
#define BDIM 512

typedef unsigned int u32;
typedef u32 u32x4 __attribute__((ext_vector_type(4)));
typedef __fp16 f16;
typedef f16 h2 __attribute__((ext_vector_type(2)));

union pun { u32 u; h2 h; };
__device__ __forceinline__ u32 h2u(h2 h) { pun p; p.h = h; return p.u; }
__device__ __forceinline__ h2 u2h(u32 u) { pun p; p.u = u; return p.h; }
__device__ __forceinline__ h2 pkh(float a, float b) { return __builtin_amdgcn_cvt_pkrtz(a, b); }

__device__ __forceinline__ float dot2(h2 a, h2 b, float c) {
    return __builtin_amdgcn_fdot2(a, b, c, false);
}
__device__ __forceinline__ float sigm(float x) { return 1.0f / (1.0f + __expf(-x)); }
__device__ __forceinline__ float tanh_f(float x) { return 2.0f / (1.0f + __expf(-2.0f * x)) - 1.0f; }

__global__ __launch_bounds__(BDIM) __attribute__((amdgpu_waves_per_eu(2, 2)))
void padd_gru_kernel(
    const float* __restrict__ xin,                       // [256,512,320]
    const float* __restrict__ h0,                        // [256,128]
    const float* __restrict__ ts0,                       // [256,64]
    const float* __restrict__ dt0,                       // [256,64]
    const float* __restrict__ w_reg, const float* __restrict__ b_reg,   // [128,64],[1]
    const float* __restrict__ w_ctl, const float* __restrict__ b_ctl,   // [128,64],[64]
    const float* __restrict__ w_dlt, const float* __restrict__ b_dlt,   // [64,128],[1]
    const float* __restrict__ w_vm,  const float* __restrict__ b_vm,    // [128,128],[1]
    const float* __restrict__ w_cor, const float* __restrict__ b_cor,   // [64,64],[64]
    const float* __restrict__ w_cat, const float* __restrict__ b_cat,   // [192,64],[1]
    const float* __restrict__ u_upd, const float* __restrict__ w_upd, const float* __restrict__ b_upd, // [128,128]x2,[1]
    const float* __restrict__ u_rst, const float* __restrict__ w_rst, const float* __restrict__ b_rst, // [128,128]x2,[1]
    float* __restrict__ out)
{
    const int t = threadIdx.x;
    const int b = blockIdx.x;

    // fp32 state / elementwise buffers
    __shared__ float h32[128];
    __shared__ float outbuf[320];   // [xreg | zcorr | c | ts | dt] = output row order
    __shared__ float tv32[64];
    __shared__ float xcur32[64];
    __shared__ float m32[64];
    __shared__ float dh32[128];
    __shared__ float z32[128];
    __shared__ float xs[320];
    __shared__ float bctl32[64];
    __shared__ float bcor32[64];
    // packed-f16 matmul activation buffers (u32 = h2 pair)
    __shared__ __align__(16) u32 hpk[64];     // h (stage A input)
    __shared__ __align__(16) u32 dtpk[32];    // dt (C1)
    __shared__ __align__(16) u32 xcpk[32];    // x_cur (C2)
    __shared__ __align__(16) u32 catpk[96];   // [m(32) | decay(64)] (D)
    __shared__ __align__(16) u32 epk[128];    // [dh(64) | c(32) | m(32)] (E; tail reused by F)
    __shared__ __align__(16) u32 rdhpk[64];   // r*dh (F)

    const int s4 = t & 3, j4 = t >> 2;   // stages A, C1, F: 128 cols, 4-way intra-wave split
    const int s8 = t & 7, j8 = t >> 3;   // stages C2, D: 64 cols, 8-way
    const int s2 = t & 1, j2 = t >> 1;   // stage E: 256 cols, 2-way

    // -------- register-resident packed-f16 weights (136 u32/thread) --------
    h2 wA[16];    // [w_reg | w_ctl] col j4, k in [32*s4, +32)
    h2 wD[8];     // w_delta col j4, k in [16*s4, +16)
    h2 wC[4];     // w_corr (diag-masked) col j8, k in [8*s8, +8)
    h2 wCt[12];   // w_concat col j8, k in [24*s8, +24)
    h2 wE[64];    // [[u_upd,u_rst],[w_upd,w_rst]] col j2, k-half s2
    h2 wF[32];    // [u_upd ; w_value_mask] col j4, k in [64*s4, +64)

    {
        const float* src = (j4 < 64) ? (w_reg + j4) : (w_ctl + (j4 - 64));
        #pragma unroll
        for (int i = 0; i < 16; i++) {
            int k = 32 * s4 + 2 * i;
            wA[i] = pkh(src[k * 64], src[(k + 1) * 64]);
        }
    }
    {
        #pragma unroll
        for (int i = 0; i < 8; i++) {
            int k = 16 * s4 + 2 * i;
            wD[i] = pkh(w_dlt[k * 128 + j4], w_dlt[(k + 1) * 128 + j4]);
        }
    }
    {
        #pragma unroll
        for (int i = 0; i < 4; i++) {
            int k = 8 * s8 + 2 * i;
            float a = (k     == j8) ? 0.f : w_cor[k * 64 + j8];
            float c = (k + 1 == j8) ? 0.f : w_cor[(k + 1) * 64 + j8];
            wC[i] = pkh(a, c);
        }
    }
    {
        #pragma unroll
        for (int i = 0; i < 12; i++) {
            int k = 24 * s8 + 2 * i;
            wCt[i] = pkh(w_cat[k * 64 + j8], w_cat[(k + 1) * 64 + j8]);
        }
    }
    {
        // stage E: rows = [u_*(128) ; w_*(128)] over [dh|c|m], cols = [upd | rst]
        const float* M = (j2 < 128) ? (s2 == 0 ? u_upd : w_upd)
                                    : (s2 == 0 ? u_rst : w_rst);
        const float* src = M + (j2 & 127);
        #pragma unroll
        for (int i = 0; i < 64; i++) {
            wE[i] = pkh(src[(2 * i) * 128], src[(2 * i + 1) * 128]);
        }
    }
    {
        const float* base = (s4 < 2) ? (u_upd + (64 * s4) * 128 + j4)
                                     : (w_vm + (64 * (s4 - 2)) * 128 + j4);
        #pragma unroll
        for (int i = 0; i < 32; i++) {
            wF[i] = pkh(base[(2 * i) * 128], base[(2 * i + 1) * 128]);
        }
    }

    const float bReg = b_reg[0];
    const float bDlt = b_dlt[0];
    const float bVm  = b_vm[0];
    const float bCat = b_cat[0];
    const float bUpd = b_upd[0];
    const float bRst = b_rst[0];

    if (t < 128) h32[t] = h0[(size_t)b * 128 + t];
    if (t < 64) {
        outbuf[192 + t] = ts0[(size_t)b * 64 + t];
        outbuf[256 + t] = dt0[(size_t)b * 64 + t];
        bctl32[t] = b_ctl[t];
        bcor32[t] = b_cor[t];
        hpk[t] = h2u(pkh(h0[(size_t)b * 128 + 2 * t], h0[(size_t)b * 128 + 2 * t + 1]));
    }

    // prefetch first input row into registers (consumed at loop top)
    float2 xpre;
    xpre.x = 0.f; xpre.y = 0.f;
    if (t < 160) {
        xpre = ((const float2*)(xin + (size_t)b * 512 * 320))[t];
    }

    __syncthreads();

    for (int st = 0; st < T_STEPS; ++st) {
        // input row regs -> LDS; issue next row's load (hidden under full step)
        if (t < 160) {
            xs[2 * t]     = xpre.x;
            xs[2 * t + 1] = xpre.y;
            int stn = (st + 1 < T_STEPS) ? (st + 1) : st;
            xpre = ((const float2*)(xin + ((size_t)b * 512 + stn) * 320))[t];
        }

        // ---- stage A: h(128) @ [w_reg | w_ctl] -> 128 cols, 4-way intra-wave
        {
            const u32x4* hp = (const u32x4*)&hpk[16 * s4];
            float a0 = 0.f, a1 = 0.f;
            #pragma unroll
            for (int q = 0; q < 4; q++) {
                u32x4 h4 = hp[q];
                a0 = dot2(wA[4*q+0], u2h(h4.x), a0);
                a1 = dot2(wA[4*q+1], u2h(h4.y), a1);
                a0 = dot2(wA[4*q+2], u2h(h4.z), a0);
                a1 = dot2(wA[4*q+3], u2h(h4.w), a1);
            }
            float v = a0 + a1;
            v += __shfl_xor(v, 1);
            v += __shfl_xor(v, 2);
            if (s4 == 0) {
                if (j4 < 64) outbuf[j4] = v + bReg;                  // x_reg
                else         tv32[j4 - 64] = fabsf(v + bctl32[j4 - 64]);
            }
        }
        __syncthreads();  // B1

        // ---- phase 2: elementwise ti/dt/x_cur (wave 0) + pack producers
        if (t < 64) {
            float ti_in = xs[t], x_in = xs[64 + t], m = xs[128 + t];
            float dt_in = xs[192 + t], pad = xs[256 + t];
            float pts = outbuf[192 + t], pdt = outbuf[256 + t];
            float tv = tv32[t], xrg = outbuf[t];
            float sum = pts + tv;
            float tic = pad * ti_in + (1.f - pad) * sum;
            float tin = (tic <= 100.0f) ? tic : pts;
            float dg  = (sum <= 100.0f) ? tv : pdt;
            float dtn = pad * dt_in + (1.f - pad) * dg;
            float xc  = m * x_in + (1.f - m) * xrg;
            outbuf[192 + t] = tin;
            outbuf[256 + t] = dtn;
            xcur32[t] = xc;
            m32[t] = m;
            float dtn2 = __shfl_down(dtn, 1);
            float xc2  = __shfl_down(xc, 1);
            float m2   = __shfl_down(m, 1);
            if ((t & 1) == 0) {
                dtpk[t >> 1] = h2u(pkh(dtn, dtn2));
                xcpk[t >> 1] = h2u(pkh(xc, xc2));
                u32 mp = h2u(pkh(m, m2));
                catpk[t >> 1] = mp;
                epk[96 + (t >> 1)] = mp;
            }
        }
        __syncthreads();  // B2

        // ---- stage C: decay-pre (dt @ w_delta, 128 cols 4-way)
        //            +  z_corr   (x_cur @ w_corr_masked, 64 cols 8-way)
        {
            const u32x4* dp = (const u32x4*)&dtpk[8 * s4];
            float a0 = 0.f, a1 = 0.f;
            #pragma unroll
            for (int q = 0; q < 2; q++) {
                u32x4 d4 = dp[q];
                a0 = dot2(wD[4*q+0], u2h(d4.x), a0);
                a1 = dot2(wD[4*q+1], u2h(d4.y), a1);
                a0 = dot2(wD[4*q+2], u2h(d4.z), a0);
                a1 = dot2(wD[4*q+3], u2h(d4.w), a1);
            }
            float vd = a0 + a1;
            vd += __shfl_xor(vd, 1);
            vd += __shfl_xor(vd, 2);

            u32x4 x4 = *(const u32x4*)&xcpk[4 * s8];
            float c0 = dot2(wC[0], u2h(x4.x), 0.f);
            float c1 = dot2(wC[1], u2h(x4.y), 0.f);
            c0 = dot2(wC[2], u2h(x4.z), c0);
            c1 = dot2(wC[3], u2h(x4.w), c1);
            float vc = c0 + c1;
            vc += __shfl_xor(vc, 1);
            vc += __shfl_xor(vc, 2);
            vc += __shfl_xor(vc, 4);

            // combine: all lanes compute (group-uniform), leaders write
            float d  = __expf(-fmaxf(vd + bDlt, 0.f));   // decay
            float dh = d * h32[j4];
            float d2  = __shfl_down(d, 4);
            float dh2 = __shfl_down(dh, 4);
            if (s4 == 0) dh32[j4] = dh;
            if ((t & 7) == 0) {
                catpk[32 + (j4 >> 1)] = h2u(pkh(d, d2));
                epk[j4 >> 1]          = h2u(pkh(dh, dh2));
                outbuf[64 + j8] = vc + bcor32[j8];       // z_corr
            }
        }
        __syncthreads();  // B3

        // ---- stage D: beta-pre = [m, decay](192) @ w_concat -> 64 cols, 8-way
        {
            const u32x4* cp = (const u32x4*)&catpk[12 * s8];
            float a0 = 0.f, a1 = 0.f;
            #pragma unroll
            for (int q = 0; q < 3; q++) {
                u32x4 c4 = cp[q];
                a0 = dot2(wCt[4*q+0], u2h(c4.x), a0);
                a1 = dot2(wCt[4*q+1], u2h(c4.y), a1);
                a0 = dot2(wCt[4*q+2], u2h(c4.z), a0);
                a1 = dot2(wCt[4*q+3], u2h(c4.w), a1);
            }
            float v = a0 + a1;
            v += __shfl_xor(v, 1);
            v += __shfl_xor(v, 2);
            v += __shfl_xor(v, 4);
            float beta = sigm(v + bCat);
            float ct = beta * outbuf[64 + j8] + (1.f - beta) * outbuf[j8];
            float m  = m32[j8];
            float c  = m * xcur32[j8] + (1.f - m) * ct;
            float c2 = __shfl_down(c, 8);
            if (s8 == 0) outbuf[128 + j8] = c;
            if ((t & 15) == 0) epk[64 + (j8 >> 1)] = h2u(pkh(c, c2));
        }
        __syncthreads();  // B4

        // ---- stage E: [dh|c|m](256) @ [[u_upd,u_rst],[w_upd,w_rst]] -> 256 cols, 2-way
        //      (weights in VGPRs; output row store overlapped here)
        {
            const u32x4* ep = (const u32x4*)&epk[64 * s2];
            float a0 = 0.f, a1 = 0.f, a2 = 0.f, a3 = 0.f;
            #pragma unroll
            for (int q = 0; q < 16; q++) {
                u32x4 e4 = ep[q];
                a0 = dot2(wE[4*q+0], u2h(e4.x), a0);
                a1 = dot2(wE[4*q+1], u2h(e4.y), a1);
                a2 = dot2(wE[4*q+2], u2h(e4.z), a2);
                a3 = dot2(wE[4*q+3], u2h(e4.w), a3);
            }
            float v = (a0 + a1) + (a2 + a3);
            v += __shfl_xor(v, 1);
            if (j2 < 128) {                  // wave-uniform branch (waves 0-3)
                float z = sigm(v + bUpd);
                if (s2 == 0) z32[j2] = z;
            } else {                         // waves 4-7
                float r = sigm(v + bRst);
                float rdh = r * dh32[j2 - 128];
                float rdh2 = __shfl_down(rdh, 2);
                if ((t & 3) == 0) rdhpk[(j2 - 128) >> 1] = h2u(pkh(rdh, rdh2));
            }
            if (t < 160) {
                float2 v2;
                v2.x = outbuf[2 * t];
                v2.y = outbuf[2 * t + 1];
                ((float2*)(out + ((size_t)st * 256 + b) * 320))[t] = v2;
            }
        }
        __syncthreads();  // B5

        // ---- stage F: [r*dh | c | m](256) @ [u_upd ; w_vm] -> 128 cols, 4-way
        {
            const u32x4* fp = (s4 & 2) ? (const u32x4*)&epk[64 + 32 * (s4 & 1)]
                                       : (const u32x4*)&rdhpk[32 * s4];
            float a0 = 0.f, a1 = 0.f;
            #pragma unroll
            for (int q = 0; q < 8; q++) {
                u32x4 f4 = fp[q];
                a0 = dot2(wF[4*q+0], u2h(f4.x), a0);
                a1 = dot2(wF[4*q+1], u2h(f4.y), a1);
                a0 = dot2(wF[4*q+2], u2h(f4.z), a0);
                a1 = dot2(wF[4*q+3], u2h(f4.w), a1);
            }
            float v = a0 + a1;
            v += __shfl_xor(v, 1);
            v += __shfl_xor(v, 2);
            float hh = tanh_f(v + bVm);
            float z = z32[j4];
            float hn = (1.f - z) * h32[j4] + z * hh;
            float hn2 = __shfl_down(hn, 4);
            if (s4 == 0) h32[j4] = hn;
            if ((t & 7) == 0) hpk[j4 >> 1] = h2u(pkh(hn, hn2));
        }
        __syncthreads();  // B6
    }

    // final carry outputs: hT, tsT, dtT
    if (t < 128) out[(size_t)41943040u + (size_t)b * 128 + t] = h32[t];
    if (t < 64) {
        out[(size_t)41975808u + (size_t)b * 64 + t] = outbuf[192 + t];
        out[(size_t)41992192u + (size_t)b * 64 + t] = outbuf[256 + t];
    }
}

extern "C" void kernel_launch(void* const* d_in, const int* in_sizes, int n_in,
                              void* d_out, int out_size, void* d_ws, size_t ws_size,
                              hipStream_t stream) {
    const float* xin   = (const float*)d_in[0];
    const float* h0    = (const float*)d_in[1];
    const float* ts0   = (const float*)d_in[2];
    const float* dt0   = (const float*)d_in[3];
    const float* w_reg = (const float*)d_in[4];
    const float* b_reg = (const float*)d_in[5];
    const float* w_ctl = (const float*)d_in[6];
    const float* b_ctl = (const float*)d_in[7];
    const float* w_dlt = (const float*)d_in[8];
    const float* b_dlt = (const float*)d_in[9];
    const float* w_vm  = (const float*)d_in[10];
    const float* b_vm  = (const float*)d_in[11];
    const float* w_cor = (const float*)d_in[12];
    const float* b_cor = (const float*)d_in[13];
    const float* w_cat = (const float*)d_in[14];
    const float* b_cat = (const float*)d_in[15];
    const float* u_upd = (const float*)d_in[16];
    const float* w_upd = (const float*)d_in[17];
    const float* b_upd = (const float*)d_in[18];
    const float* u_rst = (const float*)d_in[19];
    const float* w_rst = (const float*)d_in[20];
    const float* b_rst = (const float*)d_in[21];

    padd_gru_kernel<<<dim3(256), dim3(BDIM), 0, stream>>>(
        xin, h0, ts0, dt0,
        w_reg, b_reg, w_ctl, b_ctl, w_dlt, b_dlt, w_vm, b_vm,
        w_cor, b_cor, w_cat, b_cat,
        u_upd, w_upd, b_upd, u_rst, w_rst, b_rst,
        (float*)d_out);
}

// Round 5
// 1340.325 us; speedup vs baseline: 6.1452x; 1.1159x over previous
//
#include <hip/hip_runtime.h>
#include <stdint.h>

// PaddGRULayer: B=256, T=512, F=64, U=128. fp32 in/out.
// One persistent block per batch row (256 blocks x 512 threads, 1 block/CU).
// R5 changes vs R4 (1352 us, VALUBusy 33%, BANK_CONFLICT 1.0e8, VGPR capped 128):
//  1. __launch_bounds__(512, 2): second arg = min waves/EU -> 256-VGPR budget;
//     R4's amdgpu_waves_per_eu attribute was ignored (VGPR stayed 128, spilled).
//  2. All reductions/exchanges are now VALU: quad_perm DPP for xor1/xor2,
//     v_permlane16/32_swap for xor16/xor32 (shfl fallback). K-split bits
//     remapped {0,1,2(,3)} -> {0,1,4(,5)}; consumers' packed-weight K-order
//     permuted to match the cheap pair exchanges. Kills the 1.0e8 conflict
//     cycles (they were ds_bpermute, not wE) and ~700 cyc/step of LDS latency.
//  3. Stage-A combine fused with the elementwise pack phase (col map puts
//     x_reg[f] and tv[f] in one 8-lane group): 6 -> 5 barriers/step.
//     xs written during P4 (two barriers before next read; single buffer).
// Canary: FETCH_SIZE ~84 MB, VGPR ~190. If FETCH balloons -> spill, revert.

#define T_STEPS 512
#define BDIM 512

typedef unsigned int u32;
typedef u32 u32x4 __attribute__((ext_vector_type(4)));
typedef __fp16 f16;
typedef f16 h2 __attribute__((ext_vector_type(2)));

union pun { u32 u; h2 h; };
__device__ __forceinline__ u32 h2u(h2 h) { pun p; p.h = h; return p.u; }
__device__ __forceinline__ h2 u2h(u32 u) { pun p; p.u = u; return p.h; }
__device__ __forceinline__ h2 pkh(float a, float b) { return __builtin_amdgcn_cvt_pkrtz(a, b); }

__device__ __forceinline__ float dot2(h2 a, h2 b, float c) {
    return __builtin_amdgcn_fdot2(a, b, c, false);
}
__device__ __forceinline__ float sigm(float x) { return 1.0f / (1.0f + __expf(-x)); }
__device__ __forceinline__ float tanh_f(float x) { return 2.0f / (1.0f + __expf(-2.0f * x)) - 1.0f; }

// ---- VALU cross-lane helpers ----
// quad_perm butterfly add / exchange (xor1: ctrl 0xB1, xor2: ctrl 0x4E)
template<int CTRL>
__device__ __forceinline__ float qadd(float v) {
    int p = __builtin_amdgcn_update_dpp(0, __float_as_int(v), CTRL, 0xF, 0xF, true);
    return v + __int_as_float(p);
}
template<int CTRL>
__device__ __forceinline__ float qxchg(float v) {
    return __int_as_float(__builtin_amdgcn_update_dpp(0, __float_as_int(v), CTRL, 0xF, 0xF, true));
}
// xor16 via v_permlane16_swap (VALU), fallback shfl
__device__ __forceinline__ float x16sum(float v) {
#if __has_builtin(__builtin_amdgcn_permlane16_swap)
    auto r = __builtin_amdgcn_permlane16_swap(__float_as_uint(v), __float_as_uint(v), false, false);
    return __uint_as_float(r[0]) + __uint_as_float(r[1]);
#else
    return v + __shfl_xor(v, 16);
#endif
}
__device__ __forceinline__ float x16get(float v, int l) {
#if __has_builtin(__builtin_amdgcn_permlane16_swap)
    auto r = __builtin_amdgcn_permlane16_swap(__float_as_uint(v), __float_as_uint(v), false, false);
    return __uint_as_float((l & 16) ? r[0] : r[1]);
#else
    return __shfl_xor(v, 16);
#endif
}
__device__ __forceinline__ float x32get(float v, int l) {
#if __has_builtin(__builtin_amdgcn_permlane32_swap)
    auto r = __builtin_amdgcn_permlane32_swap(__float_as_uint(v), __float_as_uint(v), false, false);
    return __uint_as_float((l & 32) ? r[0] : r[1]);
#else
    return __shfl_xor(v, 32);
#endif
}

// pair-order helper: slot p <-> features (klo(p), klo(p)+4); klo covers all k with bit2==0
__device__ __forceinline__ int klo(int p) { return (p & 3) + 8 * (p >> 2); }

__global__ __launch_bounds__(BDIM, 2)
void padd_gru_kernel(
    const float* __restrict__ xin,                       // [256,512,320]
    const float* __restrict__ h0,                        // [256,128]
    const float* __restrict__ ts0,                       // [256,64]
    const float* __restrict__ dt0,                       // [256,64]
    const float* __restrict__ w_reg, const float* __restrict__ b_reg,   // [128,64],[1]
    const float* __restrict__ w_ctl, const float* __restrict__ b_ctl,   // [128,64],[64]
    const float* __restrict__ w_dlt, const float* __restrict__ b_dlt,   // [64,128],[1]
    const float* __restrict__ w_vm,  const float* __restrict__ b_vm,    // [128,128],[1]
    const float* __restrict__ w_cor, const float* __restrict__ b_cor,   // [64,64],[64]
    const float* __restrict__ w_cat, const float* __restrict__ b_cat,   // [192,64],[1]
    const float* __restrict__ u_upd, const float* __restrict__ w_upd, const float* __restrict__ b_upd, // [128,128]x2,[1]
    const float* __restrict__ u_rst, const float* __restrict__ w_rst, const float* __restrict__ b_rst, // [128,128]x2,[1]
    float* __restrict__ out)
{
    const int t = threadIdx.x;
    const int b = blockIdx.x;

    // fp32 state / elementwise buffers
    __shared__ float h32[128];
    __shared__ float outbuf[320];   // [xreg | zcorr | c | ts | dt] = output row order
    __shared__ float xcur32[64];
    __shared__ float m32[64];
    __shared__ float dh32[128];
    __shared__ float z32[128];
    __shared__ float xs[320];
    __shared__ float bctl32[64];
    __shared__ float bcor32[64];
    // packed-f16 activation buffers (u32 = h2 pair), pair-order = klo()
    __shared__ __align__(16) u32 hpk[64];     // h pairs (u, u+4), slot q
    __shared__ __align__(16) u32 dtpk[32];    // dt pairs (f, f+4), slot p
    __shared__ __align__(16) u32 xcpk[32];    // x_cur pairs
    __shared__ __align__(16) u32 catpk[96];   // [m p-slots(32) | decay q-slots(64)]
    __shared__ __align__(16) u32 epk[128];    // [dh q(64) | c r(32) | m p(32)]
    __shared__ __align__(16) u32 rdhpk[64];   // r*dh consecutive pairs (2s, 2s+1)

    const int l = t & 63, w = t >> 6;
    const int sA = l & 3;                       // 4-way split (A, C1, F)
    const int b23 = (l >> 2) & 3;
    const int b4 = (l >> 4) & 1, b5 = (l >> 5) & 1;
    const int fA = b23 + 4 * b5 + 8 * w;        // feature col (A-pack, C2, D), wave-exclusive
    const int uCF = b23 + 4 * ((l >> 4) & 3) + 16 * w;  // U col (C1, F), wave-exclusive
    const int s8 = (l & 3) | (b4 << 2);         // 8-way split (C2, D): bits {0,1,4}
    const int s2 = l & 1;                        // 2-way split (E)
    const int jE = ((l >> 1) & 31) + 32 * w;    // E col, wave-uniform z/r branch

    // -------- register-resident packed-f16 weights (136 u32/thread) --------
    h2 wA[16];   // A: col fA of (ctA? w_ctl : w_reg), K-slots 16*sA..+16 in hpk q-order
    h2 wD[8];    // C1: col uCF of w_dlt, K-slots 8*sA..+8 in dtpk p-order
    h2 wC[4];    // C2: col fA of masked w_cor, K-slots 4*s8..+4 in xcpk p-order
    h2 wCt[12];  // D: col fA of w_cat, K-slots 12*s8..+12 in catpk order
    h2 wE[64];   // E: col jE, K-slots 64*s2..+64 in epk order
    h2 wF[32];   // F: col uCF, K-slots 32*sA..+32 in [rdhpk | epk-c | epk-m] order

    {
        const float* src = b4 ? (w_ctl + fA) : (w_reg + fA);
        #pragma unroll
        for (int i = 0; i < 16; i++) {
            int k = klo(16 * sA + i);
            wA[i] = pkh(src[k * 64], src[(k + 4) * 64]);
        }
    }
    {
        #pragma unroll
        for (int i = 0; i < 8; i++) {
            int k = klo(8 * sA + i);
            wD[i] = pkh(w_dlt[k * 128 + uCF], w_dlt[(k + 4) * 128 + uCF]);
        }
    }
    {
        #pragma unroll
        for (int i = 0; i < 4; i++) {
            int k = klo(4 * s8 + i);
            float a = (k     == fA) ? 0.f : w_cor[k * 64 + fA];
            float c = (k + 4 == fA) ? 0.f : w_cor[(k + 4) * 64 + fA];
            wC[i] = pkh(a, c);
        }
    }
    {
        #pragma unroll
        for (int i = 0; i < 12; i++) {
            int sig = 12 * s8 + i;
            int r0 = (sig < 32) ? klo(sig) : 64 + klo(sig - 32);
            wCt[i] = pkh(w_cat[r0 * 64 + fA], w_cat[(r0 + 4) * 64 + fA]);
        }
    }
    {
        const float* MU = (jE < 128) ? u_upd : u_rst;
        const float* MW = (jE < 128) ? w_upd : w_rst;
        const int cj = jE & 127;
        #pragma unroll
        for (int i = 0; i < 64; i++) {
            int sig = 64 * s2 + i;
            const float* M; int r0;
            if (sig < 64)      { M = MU; r0 = klo(sig); }
            else if (sig < 96) { M = MW; r0 = klo(sig - 64); }
            else               { M = MW; r0 = 64 + klo(sig - 96); }
            wE[i] = pkh(M[r0 * 128 + cj], M[(r0 + 4) * 128 + cj]);
        }
    }
    {
        #pragma unroll
        for (int i = 0; i < 32; i++) {
            int sig = 32 * sA + i;
            if (sig < 64) {
                wF[i] = pkh(u_upd[(2 * sig) * 128 + uCF], u_upd[(2 * sig + 1) * 128 + uCF]);
            } else {
                int k = (sig < 96) ? klo(sig - 64) : 64 + klo(sig - 96);
                wF[i] = pkh(w_vm[k * 128 + uCF], w_vm[(k + 4) * 128 + uCF]);
            }
        }
    }

    const float bReg = b_reg[0];
    const float bDlt = b_dlt[0];
    const float bVm  = b_vm[0];
    const float bCat = b_cat[0];
    const float bUpd = b_upd[0];
    const float bRst = b_rst[0];

    if (t < 128) h32[t] = h0[(size_t)b * 128 + t];
    if (t < 64) {
        outbuf[192 + t] = ts0[(size_t)b * 64 + t];
        outbuf[256 + t] = dt0[(size_t)b * 64 + t];
        bctl32[t] = b_ctl[t];
        bcor32[t] = b_cor[t];
        int u = klo(t);
        hpk[t] = h2u(pkh(h0[(size_t)b * 128 + u], h0[(size_t)b * 128 + u + 4]));
    }

    // xs <- row 0; xpre <- row 1 (xs rewritten in P4 each step)
    float2 xpre; xpre.x = 0.f; xpre.y = 0.f;
    if (t < 160) {
        float2 x0 = ((const float2*)(xin + (size_t)b * 512 * 320))[t];
        xs[2 * t] = x0.x; xs[2 * t + 1] = x0.y;
        xpre = ((const float2*)(xin + ((size_t)b * 512 + 1) * 320))[t];
    }
    __syncthreads();

    for (int st = 0; st < T_STEPS; ++st) {
        // ---- P1: stage A (h @ [w_reg|w_ctl]) + fused elementwise pack
        {
            const u32x4* hp = (const u32x4*)&hpk[16 * sA];
            float a0 = 0.f, a1 = 0.f;
            #pragma unroll
            for (int q = 0; q < 4; q++) {
                u32x4 h4 = hp[q];
                a0 = dot2(wA[4*q+0], u2h(h4.x), a0);
                a1 = dot2(wA[4*q+1], u2h(h4.y), a1);
                a0 = dot2(wA[4*q+2], u2h(h4.z), a0);
                a1 = dot2(wA[4*q+3], u2h(h4.w), a1);
            }
            float pre = qadd<0x4E>(qadd<0xB1>(a0 + a1));
            float oth = x16get(pre, l);
            float xrg = ((l & 16) ? oth : pre) + bReg;
            float tv  = fabsf(((l & 16) ? pre : oth) + bctl32[fA]);
            float ti_in = xs[fA], x_in = xs[64 + fA], m = xs[128 + fA];
            float dt_in = xs[192 + fA], pad = xs[256 + fA];
            float pts = outbuf[192 + fA], pdt = outbuf[256 + fA];
            float sum = pts + tv;
            float tic = pad * ti_in + (1.f - pad) * sum;
            float tin = (tic <= 100.0f) ? tic : pts;
            float dg  = (sum <= 100.0f) ? tv : pdt;
            float dtn = pad * dt_in + (1.f - pad) * dg;
            float xc  = m * x_in + (1.f - m) * xrg;
            float dtn2 = x32get(dtn, l);
            float xc2  = x32get(xc, l);
            float m2   = x32get(m, l);
            if ((l & 19) == 0) {            // one lane per feature f
                outbuf[192 + fA] = tin;
                outbuf[256 + fA] = dtn;
                xcur32[fA] = xc; m32[fA] = m; outbuf[fA] = xrg;
            }
            if ((l & 51) == 0) {            // one lane per pair (f, f+4)
                int p = b23 | (w << 2);
                dtpk[p] = h2u(pkh(dtn, dtn2));
                xcpk[p] = h2u(pkh(xc, xc2));
                u32 mp = h2u(pkh(m, m2));
                catpk[p] = mp; epk[96 + p] = mp;
            }
        }
        __syncthreads();  // B1

        // ---- P2: C1 decay (dt @ w_delta) + C2 z_corr (x_cur @ w_corr_masked)
        {
            const u32x4* dp = (const u32x4*)&dtpk[8 * sA];
            float a0 = 0.f, a1 = 0.f;
            #pragma unroll
            for (int q = 0; q < 2; q++) {
                u32x4 d4 = dp[q];
                a0 = dot2(wD[4*q+0], u2h(d4.x), a0);
                a1 = dot2(wD[4*q+1], u2h(d4.y), a1);
                a0 = dot2(wD[4*q+2], u2h(d4.z), a0);
                a1 = dot2(wD[4*q+3], u2h(d4.w), a1);
            }
            float vd = qadd<0x4E>(qadd<0xB1>(a0 + a1));

            u32x4 x4 = *(const u32x4*)&xcpk[4 * s8];
            float c0 = dot2(wC[0], u2h(x4.x), 0.f);
            float c1 = dot2(wC[1], u2h(x4.y), 0.f);
            c0 = dot2(wC[2], u2h(x4.z), c0);
            c1 = dot2(wC[3], u2h(x4.w), c1);
            float vc = x16sum(qadd<0x4E>(qadd<0xB1>(c0 + c1)));

            float d  = __expf(-fmaxf(vd + bDlt, 0.f));   // decay(uCF)
            float dh = d * h32[uCF];
            float d2  = x16get(d, l);                    // decay(uCF^4)
            float dh2 = x16get(dh, l);
            if ((l & 3) == 0) dh32[uCF] = dh;
            if ((l & 19) == 0) {
                int q = b23 | ((b5 | (w << 1)) << 2);    // pair (u, u+4), u-bit2==0
                catpk[32 + q] = h2u(pkh(d, d2));
                epk[q]        = h2u(pkh(dh, dh2));
                outbuf[64 + fA] = vc + bcor32[fA];       // z_corr
            }
        }
        __syncthreads();  // B2

        // ---- P3: D beta ([m,decay] @ w_concat) + c combine
        {
            const u32x4* cp = (const u32x4*)&catpk[12 * s8];
            float a0 = 0.f, a1 = 0.f;
            #pragma unroll
            for (int q = 0; q < 3; q++) {
                u32x4 c4 = cp[q];
                a0 = dot2(wCt[4*q+0], u2h(c4.x), a0);
                a1 = dot2(wCt[4*q+1], u2h(c4.y), a1);
                a0 = dot2(wCt[4*q+2], u2h(c4.z), a0);
                a1 = dot2(wCt[4*q+3], u2h(c4.w), a1);
            }
            float v = x16sum(qadd<0x4E>(qadd<0xB1>(a0 + a1)));
            float beta = sigm(v + bCat);
            float ct = beta * outbuf[64 + fA] + (1.f - beta) * outbuf[fA];
            float m  = m32[fA];
            float c  = m * xcur32[fA] + (1.f - m) * ct;
            float c2 = x32get(c, l);
            if ((l & 19) == 0) outbuf[128 + fA] = c;
            if ((l & 51) == 0) epk[64 + (b23 | (w << 2))] = h2u(pkh(c, c2));
        }
        __syncthreads();  // B3

        // ---- P4: E ([dh|c|m] @ [[u_upd,u_rst],[w_upd,w_rst]]) + out-row store + xs stage
        {
            const u32x4* ep = (const u32x4*)&epk[64 * s2];
            float a0 = 0.f, a1 = 0.f, a2 = 0.f, a3 = 0.f;
            #pragma unroll
            for (int q = 0; q < 16; q++) {
                u32x4 e4 = ep[q];
                a0 = dot2(wE[4*q+0], u2h(e4.x), a0);
                a1 = dot2(wE[4*q+1], u2h(e4.y), a1);
                a2 = dot2(wE[4*q+2], u2h(e4.z), a2);
                a3 = dot2(wE[4*q+3], u2h(e4.w), a3);
            }
            float v = qadd<0xB1>((a0 + a1) + (a2 + a3));
            if (jE < 128) {                     // waves 0-3: z gate
                float z = sigm(v + bUpd);
                if ((l & 1) == 0) z32[jE] = z;
            } else {                            // waves 4-7: r gate -> r*dh
                float r = sigm(v + bRst);
                float rdh = r * dh32[jE - 128];
                float rdh2 = qxchg<0x4E>(rdh);  // col jE^1
                if ((l & 3) == 0) rdhpk[(jE - 128) >> 1] = h2u(pkh(rdh, rdh2));
            }
            if (t < 160) {
                float2 v2;
                v2.x = outbuf[2 * t]; v2.y = outbuf[2 * t + 1];
                ((float2*)(out + ((size_t)st * 256 + b) * 320))[t] = v2;
                xs[2 * t] = xpre.x; xs[2 * t + 1] = xpre.y;   // row st+1
                int stn = (st + 2 < T_STEPS) ? (st + 2) : (T_STEPS - 1);
                xpre = ((const float2*)(xin + ((size_t)b * 512 + stn) * 320))[t];
            }
        }
        __syncthreads();  // B4

        // ---- P5: F ([r*dh|c|m] @ [u_upd; w_vm]) + h update
        {
            const u32x4* fp = (sA < 2) ? (const u32x4*)&rdhpk[32 * sA]
                                       : (const u32x4*)&epk[64 + 32 * (sA - 2)];
            float a0 = 0.f, a1 = 0.f;
            #pragma unroll
            for (int q = 0; q < 8; q++) {
                u32x4 f4 = fp[q];
                a0 = dot2(wF[4*q+0], u2h(f4.x), a0);
                a1 = dot2(wF[4*q+1], u2h(f4.y), a1);
                a0 = dot2(wF[4*q+2], u2h(f4.z), a0);
                a1 = dot2(wF[4*q+3], u2h(f4.w), a1);
            }
            float v = qadd<0x4E>(qadd<0xB1>(a0 + a1));
            float hh = tanh_f(v + bVm);
            float z = z32[uCF];
            float hn = (1.f - z) * h32[uCF] + z * hh;
            float hn2 = x16get(hn, l);          // h(uCF^4)
            if ((l & 3) == 0) h32[uCF] = hn;
            if ((l & 19) == 0) hpk[b23 | ((b5 | (w << 1)) << 2)] = h2u(pkh(hn, hn2));
        }
        __syncthreads();  // B5
    }

    // final carry outputs: hT, tsT, dtT
    if (t < 128) out[(size_t)41943040u + (size_t)b * 128 + t] = h32[t];
    if (t < 64) {
        out[(size_t)41975808u + (size_t)b * 64 + t] = outbuf[192 + t];
        out[(size_t)41992192u + (size_t)b * 64 + t] = outbuf[256 + t];
    }
}

extern "C" void kernel_launch(void* const* d_in, const int* in_sizes, int n_in,
                              void* d_out, int out_size, void* d_ws, size_t ws_size,
                              hipStream_t stream) {
    const float* xin   = (const float*)d_in[0];
    const float* h0    = (const float*)d_in[1];
    const float* ts0   = (const float*)d_in[2];
    const float* dt0   = (const float*)d_in[3];
    const float* w_reg = (const float*)d_in[4];
    const float* b_reg = (const float*)d_in[5];
    const float* w_ctl = (const float*)d_in[6];
    const float* b_ctl = (const float*)d_in[7];
    const float* w_dlt = (const float*)d_in[8];
    const float* b_dlt = (const float*)d_in[9];
    const float* w_vm  = (const float*)d_in[10];
    const float* b_vm  = (const float*)d_in[11];
    const float* w_cor = (const float*)d_in[12];
    const float* b_cor = (const float*)d_in[13];
    const float* w_cat = (const float*)d_in[14];
    const float* b_cat = (const float*)d_in[15];
    const float* u_upd = (const float*)d_in[16];
    const float* w_upd = (const float*)d_in[17];
    const float* b_upd = (const float*)d_in[18];
    const float* u_rst = (const float*)d_in[19];
    const float* w_rst = (const float*)d_in[20];
    const float* b_rst = (const float*)d_in[21];

    padd_gru_kernel<<<dim3(256), dim3(BDIM), 0, stream>>>(
        xin, h0, ts0, dt0,
        w_reg, b_reg, w_ctl, b_ctl, w_dlt, b_dlt, w_vm, b_vm,
        w_cor, b_cor, w_cat, b_cat,
        u_upd, w_upd, b_upd, u_rst, w_rst, b_rst,
        (float*)d_out);
}